// Round 6
// baseline (762.779 us; speedup 1.0000x reference)
//
#include <hip/hip_runtime.h>
#include <cstddef>
#include <cstdint>

#define S_TOK 8192
#define DDIM  2048
#define NEXP  64
#define CAPTY 128
#define KC    64
#define TPB   64                       // tokens per chunk
#define NBLK  128                      // token chunks == gemm blocks
#define NFILL 896
#define NTOT  1024                     // 4 blocks/CU, all resident at t=0
#define SEC   ((size_t)S_TOK * NEXP * CAPTY)   // 67,108,864
// fill split: 2*SEC floats = 33,554,432 float4s = 896*36864 + 128*4096
#define FILL4_PER_FILLBLK 36864
#define FILL4_PER_GEMMBLK 4096
#define FILL4_GEMM_BASE   ((size_t)NFILL * FILL4_PER_FILLBLK)   // 33,030,144

// LDS overlay: gemm staging tiles vs block-local softmax scratch
struct GemmSm { float xs[TPB][72]; float ws2[KC][NEXP]; };       // 34,816 B
struct SoftSm { float probs[TPB][NEXP + 1]; int sexp[TPB]; };    // 16,896 B
union SMemU { GemmSm g; SoftSm s; };

// ---------------------------------------------------------------------------
// Mega kernel, fence-free / atomic-free. 1024 blocks:
//   bid <  128: full-K GEMM for token chunk bid (block-local) + softmax/
//               argmax/rank/hist in LDS, results to ws; then a small fill tail.
//   bid >= 128: stream-zero a contiguous 576 KB slice of the 537 MB output.
// Compute (~27 us VALU) hides under the HBM-write-bound fill (~85 us).
// ---------------------------------------------------------------------------
__global__ __launch_bounds__(256)
void mega_kernel(const float* __restrict__ x, const float* __restrict__ wg,
                 float* __restrict__ gate_s, int* __restrict__ expert,
                 int* __restrict__ rank, int* __restrict__ hist,
                 float* __restrict__ partial_g, float* __restrict__ out)
{
    __shared__ SMemU sm;
    const int tid = threadIdx.x;
    const int bid = blockIdx.x;
    float4* out4 = (float4*)out;
    const float4 z = make_float4(0.f, 0.f, 0.f, 0.f);

    if (bid >= NBLK) {
        // ---------------- pure fill block ----------------
        const size_t base = (size_t)(bid - NBLK) * FILL4_PER_FILLBLK;
#pragma unroll 4
        for (int it = 0; it < FILL4_PER_FILLBLK / 256; ++it)
            out4[base + (size_t)it * 256 + tid] = z;
        return;
    }

    // ---------------- gemm block: full K, block-local ----------------
    const int el = tid & 15;            // experts 4*el..4*el+3
    const int tg = tid >> 4;            // tokens  tg, tg+16, tg+32, tg+48
    const int t_base = bid * TPB;

    float acc[4][4];                    // [token i][expert j]
#pragma unroll
    for (int i = 0; i < 4; ++i)
#pragma unroll
        for (int j = 0; j < 4; ++j) acc[i][j] = 0.0f;

    for (int kc = 0; kc < DDIM; kc += KC) {
        __syncthreads();
        // stage x: 16 consecutive lanes read 256 contiguous B of one row
#pragma unroll
        for (int m = 0; m < 4; ++m) {
            int idx = tid + 256 * m;        // 0..1023
            int t = idx >> 4;               // row 0..63
            int c = idx & 15;               // float4 col 0..15
            float4 v = *(const float4*)(x + (size_t)(t_base + t) * DDIM + kc + c * 4);
            *(float4*)&sm.g.xs[t][c * 4] = v;   // aligned b128, 2-way banks
        }
        // stage wg k-major (scattered global reads, wg is 512 KB -> L2-hot;
        // LDS writes lanes e=0..63 -> 2-way banks = free)
#pragma unroll
        for (int m = 0; m < 4; ++m) {
            int idx = tid + 256 * m;
            int e = idx & 63;               // expert row
            int c = idx >> 6;               // float4 col 0..15
            float4 w = *(const float4*)(wg + (size_t)e * DDIM + kc + c * 4);
            sm.g.ws2[c * 4 + 0][e] = w.x;
            sm.g.ws2[c * 4 + 1][e] = w.y;
            sm.g.ws2[c * 4 + 2][e] = w.z;
            sm.g.ws2[c * 4 + 3][e] = w.w;
        }
        __syncthreads();

#pragma unroll
        for (int k4 = 0; k4 < KC; k4 += 4) {
            float4 xv[4], wv[4];
#pragma unroll
            for (int i = 0; i < 4; ++i)
                xv[i] = *(const float4*)&sm.g.xs[tg + 16 * i][k4];
#pragma unroll
            for (int j = 0; j < 4; ++j)
                wv[j] = *(const float4*)&sm.g.ws2[k4 + j][el * 4];
#pragma unroll
            for (int i = 0; i < 4; ++i) {
                acc[i][0] += xv[i].x * wv[0].x; acc[i][1] += xv[i].x * wv[0].y;
                acc[i][2] += xv[i].x * wv[0].z; acc[i][3] += xv[i].x * wv[0].w;
                acc[i][0] += xv[i].y * wv[1].x; acc[i][1] += xv[i].y * wv[1].y;
                acc[i][2] += xv[i].y * wv[1].z; acc[i][3] += xv[i].y * wv[1].w;
                acc[i][0] += xv[i].z * wv[2].x; acc[i][1] += xv[i].z * wv[2].y;
                acc[i][2] += xv[i].z * wv[2].z; acc[i][3] += xv[i].z * wv[2].w;
                acc[i][0] += xv[i].w * wv[3].x; acc[i][1] += xv[i].w * wv[3].y;
                acc[i][2] += xv[i].w * wv[3].z; acc[i][3] += xv[i].w * wv[3].w;
            }
        }
    }

    // ---- logits -> LDS (overlay swap: sync before reusing the union) ----
    __syncthreads();
#pragma unroll
    for (int i = 0; i < 4; ++i)
#pragma unroll
        for (int j = 0; j < 4; ++j)
            sm.s.probs[tg + 16 * i][el * 4 + j] = acc[i][j];
    __syncthreads();

    // softmax + argmax, one thread per token (row stride 65 -> conflict-free)
    if (tid < TPB) {
        const int t2 = tid, tok2 = t_base + t2;
        float m = -1e30f; int am = 0;
        for (int e = 0; e < NEXP; ++e) {
            float v = sm.s.probs[t2][e];
            if (v > m) { m = v; am = e; }       // strict > = np.argmax first-max
        }
        float s = 0.0f;
        for (int e = 0; e < NEXP; ++e) s += __expf(sm.s.probs[t2][e] - m);
        float rcp = 1.0f / s;                   // top-1 gate value
        for (int e = 0; e < NEXP; ++e)
            sm.s.probs[t2][e] = __expf(sm.s.probs[t2][e] - m) * rcp;
        sm.s.sexp[t2] = am;
        gate_s[tok2] = rcp;
        expert[tok2] = am;
    }
    __syncthreads();

    if (tid < TPB) {                    // rank within chunk (token order)
        const int t2 = tid;
        const int am = sm.s.sexp[t2];
        int r = 0;
        for (int u = 0; u < t2; ++u) r += (sm.s.sexp[u] == am) ? 1 : 0;
        rank[t_base + t2] = r;
    } else if (tid < 2 * TPB) {         // per-expert histogram + gate sums
        const int e = tid - TPB;
        float pg = 0.0f; int cnt = 0;
        for (int u = 0; u < TPB; ++u) {
            pg  += sm.s.probs[u][e];
            cnt += (sm.s.sexp[u] == e) ? 1 : 0;
        }
        partial_g[bid * NEXP + e] = pg;
        hist[bid * NEXP + e]      = cnt;
    }

    // ---------------- gemm block's small fill tail ----------------
    {
        const size_t base = FILL4_GEMM_BASE + (size_t)bid * FILL4_PER_GEMMBLK;
#pragma unroll 4
        for (int it = 0; it < FILL4_PER_GEMMBLK / 256; ++it)
            out4[base + (size_t)it * 256 + tid] = z;
        if (bid == 0 && tid == 0) out[2 * SEC] = 0.0f;  // odd last element
    }
}

// ---------------------------------------------------------------------------
// Kernel 2: per-expert exclusive scan over 128 chunks + l_aux -> ws
// ---------------------------------------------------------------------------
__global__ __launch_bounds__(64)
void scan_kernel(const int* __restrict__ hist, const float* __restrict__ partial_g,
                 int* __restrict__ chunk_base, float* __restrict__ l_aux_ws)
{
    int e = threadIdx.x;   // 0..63, one wave
    int base = 0;
    float sg = 0.0f;
    for (int c = 0; c < NBLK; ++c) {
        chunk_base[c * NEXP + e] = base;
        base += hist[c * NEXP + e];
        sg   += partial_g[c * NEXP + e];
    }
    float v = sg * (float)base;            // sum_gates[e] * pre-drop count[e]
#pragma unroll
    for (int off = 32; off > 0; off >>= 1) v += __shfl_down(v, off);
    if (e == 0)
        l_aux_ws[0] = v * (64.0f / (8192.0f * 8192.0f));   // l_aux = E/S^2 * sum
}

// ---------------------------------------------------------------------------
// Kernel 3: scatter surviving tokens + l_aux into the zeroed output
// (kernel boundary orders this after all of mega's fill writes)
// ---------------------------------------------------------------------------
__global__ __launch_bounds__(256)
void scatter_kernel(const float* __restrict__ gate_s, const int* __restrict__ expert,
                    const int* __restrict__ rank, const int* __restrict__ chunk_base,
                    const float* __restrict__ l_aux_ws, float* __restrict__ out)
{
    int s = blockIdx.x * 256 + threadIdx.x;
    if (s == 0) out[0] = l_aux_ws[0];
    if (s >= S_TOK) return;
    int e   = expert[s];
    int loc = chunk_base[(s >> 6) * NEXP + e] + rank[s];
    if (loc < CAPTY) {
        size_t idx = 1 + (size_t)s * (NEXP * CAPTY) + (size_t)e * CAPTY + loc;
        out[idx]       = gate_s[s];     // combine1_sec
        out[idx + SEC] = 1.0f;          // dispatch_mask
    }
}

extern "C" void kernel_launch(void* const* d_in, const int* in_sizes, int n_in,
                              void* d_out, int out_size, void* d_ws, size_t ws_size,
                              hipStream_t stream)
{
    const float* x  = (const float*)d_in[0];
    const float* wg = (const float*)d_in[1];
    float* out = (float*)d_out;
    char* ws = (char*)d_ws;

    size_t off = 0;
    float* gate_s    = (float*)(ws + off);          off += 32768;
    int*   expert    = (int*)  (ws + off);          off += 32768;
    int*   rank      = (int*)  (ws + off);          off += 32768;
    int*   hist      = (int*)  (ws + off);          off += 32768;
    float* partial_g = (float*)(ws + off);          off += 32768;
    int*   chunk_b   = (int*)  (ws + off);          off += 32768;
    float* l_aux_ws  = (float*)(ws + off);

    mega_kernel<<<NTOT, 256, 0, stream>>>(x, wg, gate_s, expert, rank,
                                          hist, partial_g, out);
    scan_kernel<<<1, 64, 0, stream>>>(hist, partial_g, chunk_b, l_aux_ws);
    scatter_kernel<<<(S_TOK + 255) / 256, 256, 0, stream>>>(gate_s, expert, rank,
                                                            chunk_b, l_aux_ws, out);
}

// Round 7
// 646.004 us; speedup vs baseline: 1.1808x; 1.1808x over previous
//
#include <hip/hip_runtime.h>
#include <cstddef>
#include <cstdint>

#define S_TOK 8192
#define DDIM  2048
#define NEXP  64
#define CAPTY 128
#define KC    64
#define TPB   64                       // tokens per chunk
#define NBLK  (S_TOK / TPB)            // 128 chunks
#define SPLITK 8
#define KPER  (DDIM / SPLITK)          // 256
#define SEC   ((size_t)S_TOK * NEXP * CAPTY)   // 67,108,864

// ---------------------------------------------------------------------------
// Kernel 1: split-K fp32 GEMM with register double-buffered staging.
//  xs[t][k] pad 72 (16-B aligned rows); ws[k][e].
//  Loop: barrier -> regs->LDS -> issue NEXT global loads -> barrier -> FMAs.
//  Next-tile loads are in flight during compute (hides ~900cy HBM latency).
// ---------------------------------------------------------------------------
__global__ __launch_bounds__(256)
void gate_gemm_kernel(const float* __restrict__ x, const float* __restrict__ wg,
                      float* __restrict__ part)
{
    __shared__ float xs[TPB][72];       // 18,432 B
    __shared__ float ws[KC][NEXP];      // 16,384 B

    const int tid = threadIdx.x;
    const int el  = tid & 15;           // experts 4*el..4*el+3 (and x stage col)
    const int tg  = tid >> 4;           // tokens tg+16i (and x stage row base)
    const int kp  = blockIdx.x & (SPLITK - 1);
    const int tc  = blockIdx.x >> 3;
    const int t_base = tc * TPB;
    const int k_base = kp * KPER;

    const float* xbase = x + (size_t)t_base * DDIM + k_base;
    const float* wbase = wg + k_base;
    const int we  = tid & 63;           // w stage: expert row
    const int wc0 = tid >> 6;           // w stage: float4 col base (0..3)

    float4 xr[4], wr[4];
#pragma unroll
    for (int m = 0; m < 4; ++m) {       // preload tile kc0 = 0
        xr[m] = *(const float4*)(xbase + (size_t)(tg + 16 * m) * DDIM + el * 4);
        wr[m] = *(const float4*)(wbase + (size_t)we * DDIM + (wc0 + 4 * m) * 4);
    }

    float acc[4][4];                    // [token i][expert j]
#pragma unroll
    for (int i = 0; i < 4; ++i)
#pragma unroll
        for (int j = 0; j < 4; ++j) acc[i][j] = 0.0f;

    for (int kc0 = 0; kc0 < KPER; kc0 += KC) {
        __syncthreads();                // previous compute finished with LDS
#pragma unroll
        for (int m = 0; m < 4; ++m) {   // regs -> LDS
            *(float4*)&xs[tg + 16 * m][el * 4] = xr[m];
            const int c = wc0 + 4 * m;
            ws[c * 4 + 0][we] = wr[m].x;
            ws[c * 4 + 1][we] = wr[m].y;
            ws[c * 4 + 2][we] = wr[m].z;
            ws[c * 4 + 3][we] = wr[m].w;
        }
        if (kc0 + KC < KPER) {          // issue NEXT tile loads (fly during FMAs)
#pragma unroll
            for (int m = 0; m < 4; ++m) {
                xr[m] = *(const float4*)(xbase + (size_t)(tg + 16 * m) * DDIM + kc0 + KC + el * 4);
                wr[m] = *(const float4*)(wbase + (size_t)we * DDIM + kc0 + KC + (wc0 + 4 * m) * 4);
            }
        }
        __syncthreads();                // LDS tile visible

#pragma unroll
        for (int k4 = 0; k4 < KC; k4 += 4) {
            float4 xv[4], wv[4];
#pragma unroll
            for (int i = 0; i < 4; ++i)
                xv[i] = *(const float4*)&xs[tg + 16 * i][k4];    // 16-lane broadcast
#pragma unroll
            for (int j = 0; j < 4; ++j)
                wv[j] = *(const float4*)&ws[k4 + j][el * 4];     // 4-lane broadcast
#pragma unroll
            for (int i = 0; i < 4; ++i) {
                acc[i][0] += xv[i].x * wv[0].x; acc[i][1] += xv[i].x * wv[0].y;
                acc[i][2] += xv[i].x * wv[0].z; acc[i][3] += xv[i].x * wv[0].w;
                acc[i][0] += xv[i].y * wv[1].x; acc[i][1] += xv[i].y * wv[1].y;
                acc[i][2] += xv[i].y * wv[1].z; acc[i][3] += xv[i].y * wv[1].w;
                acc[i][0] += xv[i].z * wv[2].x; acc[i][1] += xv[i].z * wv[2].y;
                acc[i][2] += xv[i].z * wv[2].z; acc[i][3] += xv[i].z * wv[2].w;
                acc[i][0] += xv[i].w * wv[3].x; acc[i][1] += xv[i].w * wv[3].y;
                acc[i][2] += xv[i].w * wv[3].z; acc[i][3] += xv[i].w * wv[3].w;
            }
        }
    }

#pragma unroll
    for (int i = 0; i < 4; ++i) {
        int t = tg + 16 * i;
        float4 v = make_float4(acc[i][0], acc[i][1], acc[i][2], acc[i][3]);
        *(float4*)(part + ((size_t)kp * S_TOK + t_base + t) * NEXP + el * 4) = v;
    }
}

// ---------------------------------------------------------------------------
// Kernel 2: reduce split-K partials + softmax/argmax/rank/hist per chunk.
// 128 blocks x 256 threads (4 threads per token for the reduction).
// ---------------------------------------------------------------------------
__global__ __launch_bounds__(256)
void softmax_kernel(const float* __restrict__ part,
                    float* __restrict__ gate_s, int* __restrict__ expert,
                    int* __restrict__ rank, int* __restrict__ hist,
                    float* __restrict__ partial_g)
{
    __shared__ float probs[TPB][NEXP + 1];
    __shared__ int   sexp[TPB];

    const int tid = threadIdx.x;
    const int t_base = blockIdx.x * TPB;
    const int t = tid >> 2, q = tid & 3;    // 4 threads per token
    const int tok = t_base + t;

#pragma unroll
    for (int jj = 0; jj < 4; ++jj) {
        float4 a = make_float4(0.f, 0.f, 0.f, 0.f);
#pragma unroll
        for (int kpp = 0; kpp < SPLITK; ++kpp) {
            float4 v = *(const float4*)(part + ((size_t)kpp * S_TOK + tok) * NEXP + q * 16 + jj * 4);
            a.x += v.x; a.y += v.y; a.z += v.z; a.w += v.w;
        }
        probs[t][q * 16 + jj * 4 + 0] = a.x;
        probs[t][q * 16 + jj * 4 + 1] = a.y;
        probs[t][q * 16 + jj * 4 + 2] = a.z;
        probs[t][q * 16 + jj * 4 + 3] = a.w;
    }
    __syncthreads();

    if (tid < TPB) {                    // one thread per token
        const int t2 = tid, tok2 = t_base + t2;
        float m = -1e30f; int am = 0;
        for (int e = 0; e < NEXP; ++e) {
            float v = probs[t2][e];
            if (v > m) { m = v; am = e; }       // strict > = np.argmax first-max
        }
        float s = 0.0f;
        for (int e = 0; e < NEXP; ++e) s += __expf(probs[t2][e] - m);
        float rcp = 1.0f / s;                   // top-1 gate value
        for (int e = 0; e < NEXP; ++e)
            probs[t2][e] = __expf(probs[t2][e] - m) * rcp;
        sexp[t2] = am;
        gate_s[tok2] = rcp;
        expert[tok2] = am;
    }
    __syncthreads();

    if (tid < TPB) {                    // rank within chunk (token order)
        const int t2 = tid;
        const int am = sexp[t2];
        int r = 0;
        for (int u = 0; u < t2; ++u) r += (sexp[u] == am) ? 1 : 0;
        rank[t_base + t2] = r;
    } else if (tid < 2 * TPB) {         // per-expert histogram + gate sums
        const int e = tid - TPB;
        float pg = 0.0f; int cnt = 0;
        for (int u = 0; u < TPB; ++u) {
            pg  += probs[u][e];
            cnt += (sexp[u] == e) ? 1 : 0;
        }
        partial_g[blockIdx.x * NEXP + e] = pg;
        hist[blockIdx.x * NEXP + e]      = cnt;
    }
}

// ---------------------------------------------------------------------------
// Kernel 3: per-expert exclusive scan (unrolled for MLP) + l_aux + scatter.
// Runs after the memset -> safe to write out[0] and scatter.
// ---------------------------------------------------------------------------
__global__ __launch_bounds__(256)
void scan_scatter_kernel(const int* __restrict__ hist, const float* __restrict__ partial_g,
                         const float* __restrict__ gate_s, const int* __restrict__ expert,
                         const int* __restrict__ rank, float* __restrict__ out)
{
    __shared__ int base_s[NBLK][NEXP];      // 32 KB
    const int tid = threadIdx.x;

    if (tid < NEXP) {                       // wave 0: scan per expert
        const int e = tid;
        int base = 0; float sg = 0.0f;
#pragma unroll 16
        for (int c = 0; c < NBLK; ++c) {
            base_s[c][e] = base;
            base += hist[c * NEXP + e];
            sg  += partial_g[c * NEXP + e];
        }
        float v = sg * (float)base;         // sum_gates[e] * pre-drop count[e]
#pragma unroll
        for (int off = 32; off > 0; off >>= 1) v += __shfl_down(v, off);
        if (e == 0) out[0] = v * (64.0f / (8192.0f * 8192.0f));   // l_aux
    }
    __syncthreads();

    for (int s = tid; s < S_TOK; s += 256) {
        const int e = expert[s];
        const int loc = base_s[s >> 6][e] + rank[s];
        if (loc < CAPTY) {
            size_t idx = 1 + (size_t)s * (NEXP * CAPTY) + (size_t)e * CAPTY + loc;
            out[idx]       = gate_s[s];     // combine1_sec
            out[idx + SEC] = 1.0f;          // dispatch_mask
        }
    }
}

extern "C" void kernel_launch(void* const* d_in, const int* in_sizes, int n_in,
                              void* d_out, int out_size, void* d_ws, size_t ws_size,
                              hipStream_t stream)
{
    const float* x  = (const float*)d_in[0];
    const float* wg = (const float*)d_in[1];
    float* out = (float*)d_out;
    char* ws = (char*)d_ws;

    float* part      = (float*)(ws + 0);                       // 16 MB
    size_t off = (size_t)SPLITK * S_TOK * NEXP * sizeof(float);
    float* gate_s    = (float*)(ws + off);          off += 32768;
    int*   expert    = (int*)  (ws + off);          off += 32768;
    int*   rank      = (int*)  (ws + off);          off += 32768;
    int*   hist      = (int*)  (ws + off);          off += 32768;
    float* partial_g = (float*)(ws + off);

    gate_gemm_kernel<<<NBLK * SPLITK, 256, 0, stream>>>(x, wg, part);
    softmax_kernel<<<NBLK, 256, 0, stream>>>(part, gate_s, expert, rank, hist, partial_g);
    // 537 MB zero-fill on the rocclr fill path (measured ~6.3 TB/s)
    hipMemsetAsync(d_out, 0, (size_t)out_size * sizeof(float), stream);
    scan_scatter_kernel<<<1, 256, 0, stream>>>(hist, partial_g, gate_s, expert, rank, out);
}

// Round 8
// 615.926 us; speedup vs baseline: 1.2384x; 1.0488x over previous
//
#include <hip/hip_runtime.h>
#include <cstddef>
#include <cstdint>

#define S_TOK 8192
#define DDIM  2048
#define NEXP  64
#define CAPTY 128
#define KC    64
#define TPB   64                       // tokens per chunk
#define NBLK  (S_TOK / TPB)            // 128 chunks
#define SPLITK 8
#define KPER  (DDIM / SPLITK)          // 256
#define SEC   ((size_t)S_TOK * NEXP * CAPTY)   // 67,108,864
#define ROW   (NEXP * CAPTY)           // 8192 floats per token row
#define TOK_PER_FB 2                   // tokens per fill block
#define NFB   (S_TOK / TOK_PER_FB)     // 4096 fill blocks

// ---------------------------------------------------------------------------
// Kernel 1: split-K fp32 GEMM (byte-identical to round-5 best).
//  x staged t-major xs[t][k] (row pad 72: 16-B aligned, 2-way banks).
//  wg staged k-major ws[k][e] (scattered global reads; wg is L2-hot).
// ---------------------------------------------------------------------------
__global__ __launch_bounds__(256)
void gate_gemm_kernel(const float* __restrict__ x, const float* __restrict__ wg,
                      float* __restrict__ part)
{
    __shared__ float xs[TPB][72];       // 18,432 B
    __shared__ float ws[KC][NEXP];      // 16,384 B

    const int tid = threadIdx.x;
    const int el  = tid & 15;           // experts 4*el..4*el+3
    const int tg  = tid >> 4;           // tokens  tg, tg+16, tg+32, tg+48
    const int kp  = blockIdx.x & (SPLITK - 1);
    const int tc  = blockIdx.x >> 3;
    const int t_base = tc * TPB;
    const int k_base = kp * KPER;

    float acc[4][4];                    // [token i][expert j]
#pragma unroll
    for (int i = 0; i < 4; ++i)
#pragma unroll
        for (int j = 0; j < 4; ++j) acc[i][j] = 0.0f;

    for (int kc0 = 0; kc0 < KPER; kc0 += KC) {
        const int kc = k_base + kc0;
        __syncthreads();
        // stage x: 16 consecutive lanes read 256 contiguous bytes of one row
#pragma unroll
        for (int m = 0; m < 4; ++m) {
            int idx = tid + 256 * m;        // 0..1023
            int t = idx >> 4;               // row 0..63
            int c = idx & 15;               // float4 col 0..15
            float4 v = *(const float4*)(x + (size_t)(t_base + t) * DDIM + kc + c * 4);
            *(float4*)&xs[t][c * 4] = v;    // aligned b128, ~2-way banks
        }
        // stage wg k-major (scattered global reads, L2-absorbed)
#pragma unroll
        for (int m = 0; m < 4; ++m) {
            int idx = tid + 256 * m;
            int e = idx & 63;               // expert row
            int c = idx >> 6;               // float4 col 0..15
            float4 w = *(const float4*)(wg + (size_t)e * DDIM + kc + c * 4);
            ws[c * 4 + 0][e] = w.x;
            ws[c * 4 + 1][e] = w.y;
            ws[c * 4 + 2][e] = w.z;
            ws[c * 4 + 3][e] = w.w;
        }
        __syncthreads();

#pragma unroll
        for (int k4 = 0; k4 < KC; k4 += 4) {
            float4 xv[4], wv[4];
#pragma unroll
            for (int i = 0; i < 4; ++i)
                xv[i] = *(const float4*)&xs[tg + 16 * i][k4];
#pragma unroll
            for (int j = 0; j < 4; ++j)
                wv[j] = *(const float4*)&ws[k4 + j][el * 4];
#pragma unroll
            for (int i = 0; i < 4; ++i) {
                acc[i][0] += xv[i].x * wv[0].x; acc[i][1] += xv[i].x * wv[0].y;
                acc[i][2] += xv[i].x * wv[0].z; acc[i][3] += xv[i].x * wv[0].w;
                acc[i][0] += xv[i].y * wv[1].x; acc[i][1] += xv[i].y * wv[1].y;
                acc[i][2] += xv[i].y * wv[1].z; acc[i][3] += xv[i].y * wv[1].w;
                acc[i][0] += xv[i].z * wv[2].x; acc[i][1] += xv[i].z * wv[2].y;
                acc[i][2] += xv[i].z * wv[2].z; acc[i][3] += xv[i].z * wv[2].w;
                acc[i][0] += xv[i].w * wv[3].x; acc[i][1] += xv[i].w * wv[3].y;
                acc[i][2] += xv[i].w * wv[3].z; acc[i][3] += xv[i].w * wv[3].w;
            }
        }
    }

#pragma unroll
    for (int i = 0; i < 4; ++i) {
        int t = tg + 16 * i;
        float4 v = make_float4(acc[i][0], acc[i][1], acc[i][2], acc[i][3]);
        *(float4*)(part + ((size_t)kp * S_TOK + t_base + t) * NEXP + el * 4) = v;
    }
}

// ---------------------------------------------------------------------------
// Kernel 2: reduce split-K partials + softmax/argmax/rank/hist per chunk.
// (byte-identical to round-5 best)
// ---------------------------------------------------------------------------
__global__ __launch_bounds__(256)
void softmax_kernel(const float* __restrict__ part,
                    float* __restrict__ gate_s, int* __restrict__ expert,
                    int* __restrict__ rank, int* __restrict__ hist,
                    float* __restrict__ partial_g)
{
    __shared__ float probs[TPB][NEXP + 1];
    __shared__ int   sexp[TPB];

    const int tid = threadIdx.x;
    const int t_base = blockIdx.x * TPB;
    const int t = tid >> 2, q = tid & 3;    // 4 threads per token
    const int tok = t_base + t;

#pragma unroll
    for (int jj = 0; jj < 4; ++jj) {
        float4 a = make_float4(0.f, 0.f, 0.f, 0.f);
#pragma unroll
        for (int kpp = 0; kpp < SPLITK; ++kpp) {
            float4 v = *(const float4*)(part + ((size_t)kpp * S_TOK + tok) * NEXP + q * 16 + jj * 4);
            a.x += v.x; a.y += v.y; a.z += v.z; a.w += v.w;
        }
        probs[t][q * 16 + jj * 4 + 0] = a.x;
        probs[t][q * 16 + jj * 4 + 1] = a.y;
        probs[t][q * 16 + jj * 4 + 2] = a.z;
        probs[t][q * 16 + jj * 4 + 3] = a.w;
    }
    __syncthreads();

    if (tid < TPB) {                    // one thread per token
        const int t2 = tid, tok2 = t_base + t2;
        float m = -1e30f; int am = 0;
        for (int e = 0; e < NEXP; ++e) {
            float v = probs[t2][e];
            if (v > m) { m = v; am = e; }       // strict > = np.argmax first-max
        }
        float s = 0.0f;
        for (int e = 0; e < NEXP; ++e) s += __expf(probs[t2][e] - m);
        float rcp = 1.0f / s;                   // top-1 gate value
        for (int e = 0; e < NEXP; ++e)
            probs[t2][e] = __expf(probs[t2][e] - m) * rcp;
        sexp[t2] = am;
        gate_s[tok2] = rcp;
        expert[tok2] = am;
    }
    __syncthreads();

    if (tid < TPB) {                    // rank within chunk (token order)
        const int t2 = tid;
        const int am = sexp[t2];
        int r = 0;
        for (int u = 0; u < t2; ++u) r += (sexp[u] == am) ? 1 : 0;
        rank[t_base + t2] = r;
    } else if (tid < 2 * TPB) {         // per-expert histogram + gate sums
        const int e = tid - TPB;
        float pg = 0.0f; int cnt = 0;
        for (int u = 0; u < TPB; ++u) {
            pg  += probs[u][e];
            cnt += (sexp[u] == e) ? 1 : 0;
        }
        partial_g[blockIdx.x * NEXP + e] = pg;
        hist[blockIdx.x * NEXP + e]      = cnt;
    }
}

// ---------------------------------------------------------------------------
// Kernel 3: per-expert exclusive scan over 128 chunks (unrolled) + l_aux
// -> ws.  Runs BEFORE the fill so hist/partial_g are L2-hot.
// ---------------------------------------------------------------------------
__global__ __launch_bounds__(64)
void scan_kernel(const int* __restrict__ hist, const float* __restrict__ partial_g,
                 int* __restrict__ chunk_base, float* __restrict__ l_aux_ws)
{
    int e = threadIdx.x;   // 0..63, one wave
    int base = 0;
    float sg = 0.0f;
#pragma unroll 8
    for (int c = 0; c < NBLK; ++c) {
        chunk_base[c * NEXP + e] = base;
        base += hist[c * NEXP + e];
        sg   += partial_g[c * NEXP + e];
    }
    float v = sg * (float)base;            // sum_gates[e] * pre-drop count[e]
#pragma unroll
    for (int off = 32; off > 0; off >>= 1) v += __shfl_down(v, off);
    if (e == 0)
        l_aux_ws[0] = v * (64.0f / (8192.0f * 8192.0f));   // l_aux = E/S^2 * sum
}

// ---------------------------------------------------------------------------
// Kernel 4: homogeneous fill+scatter. 4096 identical blocks; block b owns
// tokens {2b, 2b+1}: zeroes their combine rows [1+s*ROW, 1+(s+1)*ROW) and
// dispatch rows (+SEC), then overwrites its own <=2 gate entries (block-local
// ordering via __syncthreads; no cross-block dependency anywhere).
// ---------------------------------------------------------------------------
__global__ __launch_bounds__(256)
void fill_scatter_kernel(const float* __restrict__ gate_s, const int* __restrict__ expert,
                         const int* __restrict__ rank, const int* __restrict__ chunk_base,
                         const float* __restrict__ l_aux_ws, float* __restrict__ out)
{
    const int tid = threadIdx.x;
    const int b   = blockIdx.x;
    const size_t C0 = 1 + (size_t)b * (TOK_PER_FB * ROW);   // combine region start
    const size_t LEN = TOK_PER_FB * ROW;                    // 16384 floats
    const float4 z = make_float4(0.f, 0.f, 0.f, 0.f);

    // zero both regions: start ≡ 1 (mod 4) -> 3-scalar head, float4 body, 1 tail
#pragma unroll
    for (int half = 0; half < 2; ++half) {
        const size_t R0 = C0 + (size_t)half * SEC;
        const size_t a0 = R0 + 3;                  // 16-B aligned
        const size_t a1 = R0 + LEN - 1;            // aligned end (len-4 body floats)
        float4* body = (float4*)(out + a0);
        const int n4 = (int)((a1 - a0) >> 2);      // 4095 float4s
#pragma unroll
        for (int it = 0; it < 16; ++it) {
            int i = it * 256 + tid;
            if (i < n4) body[i] = z;
        }
        if (tid < 3) out[R0 + tid] = 0.0f;         // head scalars
        else if (tid == 3) out[R0 + LEN - 1] = 0.0f;   // tail scalar
    }
    __syncthreads();                               // zeros done before scatter

    if (tid < TOK_PER_FB) {                        // scatter this block's tokens
        const int s = b * TOK_PER_FB + tid;
        const int e = expert[s];
        const int loc = chunk_base[(s >> 6) * NEXP + e] + rank[s];
        if (loc < CAPTY) {
            size_t idx = 1 + (size_t)s * ROW + (size_t)e * CAPTY + loc;
            out[idx]       = gate_s[s];            // combine1_sec
            out[idx + SEC] = 1.0f;                 // dispatch_mask
        }
    } else if (b == 0 && tid == 255) {
        out[0] = l_aux_ws[0];                      // l_aux (outside all regions)
    }
}

extern "C" void kernel_launch(void* const* d_in, const int* in_sizes, int n_in,
                              void* d_out, int out_size, void* d_ws, size_t ws_size,
                              hipStream_t stream)
{
    const float* x  = (const float*)d_in[0];
    const float* wg = (const float*)d_in[1];
    float* out = (float*)d_out;
    char* ws = (char*)d_ws;

    float* part      = (float*)(ws + 0);                       // 16 MB
    size_t off = (size_t)SPLITK * S_TOK * NEXP * sizeof(float);
    float* gate_s    = (float*)(ws + off);          off += 32768;
    int*   expert    = (int*)  (ws + off);          off += 32768;
    int*   rank      = (int*)  (ws + off);          off += 32768;
    int*   hist      = (int*)  (ws + off);          off += 32768;
    float* partial_g = (float*)(ws + off);          off += 32768;
    int*   chunk_b   = (int*)  (ws + off);          off += 32768;
    float* l_aux_ws  = (float*)(ws + off);

    gate_gemm_kernel<<<NBLK * SPLITK, 256, 0, stream>>>(x, wg, part);
    softmax_kernel<<<NBLK, 256, 0, stream>>>(part, gate_s, expert, rank, hist, partial_g);
    scan_kernel<<<1, 64, 0, stream>>>(hist, partial_g, chunk_b, l_aux_ws);
    fill_scatter_kernel<<<NFB, 256, 0, stream>>>(gate_s, expert, rank, chunk_b,
                                                 l_aux_ws, out);
}

// Round 9
// 596.007 us; speedup vs baseline: 1.2798x; 1.0334x over previous
//
#include <hip/hip_runtime.h>
#include <cstddef>
#include <cstdint>

#define S_TOK 8192
#define DDIM  2048
#define NEXP  64
#define CAPTY 128
#define KC    64
#define TPB   64                       // tokens per chunk
#define NBLK  (S_TOK / TPB)            // 128 chunks
#define SPLITK 8
#define KPER  (DDIM / SPLITK)          // 256
#define SEC   ((size_t)S_TOK * NEXP * CAPTY)   // 67,108,864

// ---------------------------------------------------------------------------
// BEST MEASURED STRUCTURE (round 5, 595.5 us). All producer->consumer edges
// are kernel boundaries (no fences/atomics: device-scope fences collapsed BW
// to ~1.2 TB/s in rounds 3/4; heterogeneous block roles in one dispatch were
// equally toxic in round 6). Fill uses the rocclr memset path (measured
// 6.3 TB/s; beats hand-rolled fill with tail predication, round 8).
// ---------------------------------------------------------------------------

// Kernel 1: split-K fp32 GEMM.
//  x staged t-major xs[t][k] (row pad 72: 16-B aligned rows, 2-way banks).
//  wg staged k-major ws[k][e] (scattered global reads; wg slice is L2-hot).
__global__ __launch_bounds__(256)
void gate_gemm_kernel(const float* __restrict__ x, const float* __restrict__ wg,
                      float* __restrict__ part)
{
    __shared__ float xs[TPB][72];       // 18,432 B
    __shared__ float ws[KC][NEXP];      // 16,384 B  (34.8 KB -> 4 blk/CU)

    const int tid = threadIdx.x;
    const int el  = tid & 15;           // experts 4*el..4*el+3
    const int tg  = tid >> 4;           // tokens  tg, tg+16, tg+32, tg+48
    const int kp  = blockIdx.x & (SPLITK - 1);
    const int tc  = blockIdx.x >> 3;
    const int t_base = tc * TPB;
    const int k_base = kp * KPER;

    float acc[4][4];                    // [token i][expert j]
#pragma unroll
    for (int i = 0; i < 4; ++i)
#pragma unroll
        for (int j = 0; j < 4; ++j) acc[i][j] = 0.0f;

    for (int kc0 = 0; kc0 < KPER; kc0 += KC) {
        const int kc = k_base + kc0;
        __syncthreads();
        // stage x: 16 consecutive lanes read 256 contiguous bytes of one row
#pragma unroll
        for (int m = 0; m < 4; ++m) {
            int idx = tid + 256 * m;        // 0..1023
            int t = idx >> 4;               // row 0..63
            int c = idx & 15;               // float4 col 0..15
            float4 v = *(const float4*)(x + (size_t)(t_base + t) * DDIM + kc + c * 4);
            *(float4*)&xs[t][c * 4] = v;    // aligned b128, ~2-way banks
        }
        // stage wg k-major (scattered global reads, L2-absorbed)
#pragma unroll
        for (int m = 0; m < 4; ++m) {
            int idx = tid + 256 * m;
            int e = idx & 63;               // expert row
            int c = idx >> 6;               // float4 col 0..15
            float4 w = *(const float4*)(wg + (size_t)e * DDIM + kc + c * 4);
            ws[c * 4 + 0][e] = w.x;
            ws[c * 4 + 1][e] = w.y;
            ws[c * 4 + 2][e] = w.z;
            ws[c * 4 + 3][e] = w.w;
        }
        __syncthreads();

#pragma unroll
        for (int k4 = 0; k4 < KC; k4 += 4) {
            float4 xv[4], wv[4];
#pragma unroll
            for (int i = 0; i < 4; ++i)
                xv[i] = *(const float4*)&xs[tg + 16 * i][k4];
#pragma unroll
            for (int j = 0; j < 4; ++j)
                wv[j] = *(const float4*)&ws[k4 + j][el * 4];
#pragma unroll
            for (int i = 0; i < 4; ++i) {
                acc[i][0] += xv[i].x * wv[0].x; acc[i][1] += xv[i].x * wv[0].y;
                acc[i][2] += xv[i].x * wv[0].z; acc[i][3] += xv[i].x * wv[0].w;
                acc[i][0] += xv[i].y * wv[1].x; acc[i][1] += xv[i].y * wv[1].y;
                acc[i][2] += xv[i].y * wv[1].z; acc[i][3] += xv[i].y * wv[1].w;
                acc[i][0] += xv[i].z * wv[2].x; acc[i][1] += xv[i].z * wv[2].y;
                acc[i][2] += xv[i].z * wv[2].z; acc[i][3] += xv[i].z * wv[2].w;
                acc[i][0] += xv[i].w * wv[3].x; acc[i][1] += xv[i].w * wv[3].y;
                acc[i][2] += xv[i].w * wv[3].z; acc[i][3] += xv[i].w * wv[3].w;
            }
        }
    }

#pragma unroll
    for (int i = 0; i < 4; ++i) {
        int t = tg + 16 * i;
        float4 v = make_float4(acc[i][0], acc[i][1], acc[i][2], acc[i][3]);
        *(float4*)(part + ((size_t)kp * S_TOK + t_base + t) * NEXP + el * 4) = v;
    }
}

// Kernel 2: reduce split-K partials + softmax/argmax/rank/hist per chunk.
__global__ __launch_bounds__(256)
void softmax_kernel(const float* __restrict__ part,
                    float* __restrict__ gate_s, int* __restrict__ expert,
                    int* __restrict__ rank, int* __restrict__ hist,
                    float* __restrict__ partial_g)
{
    __shared__ float probs[TPB][NEXP + 1];
    __shared__ int   sexp[TPB];

    const int tid = threadIdx.x;
    const int t_base = blockIdx.x * TPB;
    const int t = tid >> 2, q = tid & 3;    // 4 threads per token
    const int tok = t_base + t;

#pragma unroll
    for (int jj = 0; jj < 4; ++jj) {
        float4 a = make_float4(0.f, 0.f, 0.f, 0.f);
#pragma unroll
        for (int kpp = 0; kpp < SPLITK; ++kpp) {
            float4 v = *(const float4*)(part + ((size_t)kpp * S_TOK + tok) * NEXP + q * 16 + jj * 4);
            a.x += v.x; a.y += v.y; a.z += v.z; a.w += v.w;
        }
        probs[t][q * 16 + jj * 4 + 0] = a.x;
        probs[t][q * 16 + jj * 4 + 1] = a.y;
        probs[t][q * 16 + jj * 4 + 2] = a.z;
        probs[t][q * 16 + jj * 4 + 3] = a.w;
    }
    __syncthreads();

    if (tid < TPB) {                    // one thread per token
        const int t2 = tid, tok2 = t_base + t2;
        float m = -1e30f; int am = 0;
        for (int e = 0; e < NEXP; ++e) {
            float v = probs[t2][e];
            if (v > m) { m = v; am = e; }       // strict > = np.argmax first-max
        }
        float s = 0.0f;
        for (int e = 0; e < NEXP; ++e) s += __expf(probs[t2][e] - m);
        float rcp = 1.0f / s;                   // top-1 gate value
        for (int e = 0; e < NEXP; ++e)
            probs[t2][e] = __expf(probs[t2][e] - m) * rcp;
        sexp[t2] = am;
        gate_s[tok2] = rcp;
        expert[tok2] = am;
    }
    __syncthreads();

    if (tid < TPB) {                    // rank within chunk (token order)
        const int t2 = tid;
        const int am = sexp[t2];
        int r = 0;
        for (int u = 0; u < t2; ++u) r += (sexp[u] == am) ? 1 : 0;
        rank[t_base + t2] = r;
    } else if (tid < 2 * TPB) {         // per-expert histogram + gate sums
        const int e = tid - TPB;
        float pg = 0.0f; int cnt = 0;
        for (int u = 0; u < TPB; ++u) {
            pg  += probs[u][e];
            cnt += (sexp[u] == e) ? 1 : 0;
        }
        partial_g[blockIdx.x * NEXP + e] = pg;
        hist[blockIdx.x * NEXP + e]      = cnt;
    }
}

// Kernel 3: per-expert exclusive scan over 128 chunks + l_aux -> ws
// (runs BEFORE the big fill so only the tiny scatter trails it)
__global__ __launch_bounds__(64)
void scan_kernel(const int* __restrict__ hist, const float* __restrict__ partial_g,
                 int* __restrict__ chunk_base, float* __restrict__ l_aux_ws)
{
    int e = threadIdx.x;   // 0..63, one wave
    int base = 0;
    float sg = 0.0f;
    for (int c = 0; c < NBLK; ++c) {
        chunk_base[c * NEXP + e] = base;
        base += hist[c * NEXP + e];
        sg   += partial_g[c * NEXP + e];
    }
    float v = sg * (float)base;            // sum_gates[e] * pre-drop count[e]
#pragma unroll
    for (int off = 32; off > 0; off >>= 1) v += __shfl_down(v, off);
    if (e == 0)
        l_aux_ws[0] = v * (64.0f / (8192.0f * 8192.0f));   // l_aux = E/S^2 * sum
}

// Kernel 4: scatter surviving tokens + l_aux into the zeroed output
__global__ __launch_bounds__(256)
void scatter_kernel(const float* __restrict__ gate_s, const int* __restrict__ expert,
                    const int* __restrict__ rank, const int* __restrict__ chunk_base,
                    const float* __restrict__ l_aux_ws, float* __restrict__ out)
{
    int s = blockIdx.x * 256 + threadIdx.x;
    if (s == 0) out[0] = l_aux_ws[0];
    if (s >= S_TOK) return;
    int e   = expert[s];
    int loc = chunk_base[(s >> 6) * NEXP + e] + rank[s];
    if (loc < CAPTY) {
        size_t idx = 1 + (size_t)s * (NEXP * CAPTY) + (size_t)e * CAPTY + loc;
        out[idx]       = gate_s[s];     // combine1_sec
        out[idx + SEC] = 1.0f;          // dispatch_mask
    }
}

extern "C" void kernel_launch(void* const* d_in, const int* in_sizes, int n_in,
                              void* d_out, int out_size, void* d_ws, size_t ws_size,
                              hipStream_t stream)
{
    const float* x  = (const float*)d_in[0];
    const float* wg = (const float*)d_in[1];
    float* out = (float*)d_out;
    char* ws = (char*)d_ws;

    float* part      = (float*)(ws + 0);                       // 16 MB
    size_t off = (size_t)SPLITK * S_TOK * NEXP * sizeof(float);
    float* gate_s    = (float*)(ws + off);          off += 32768;
    int*   expert    = (int*)  (ws + off);          off += 32768;
    int*   rank      = (int*)  (ws + off);          off += 32768;
    int*   hist      = (int*)  (ws + off);          off += 32768;
    float* partial_g = (float*)(ws + off);          off += 32768;
    int*   chunk_b   = (int*)  (ws + off);          off += 32768;
    float* l_aux_ws  = (float*)(ws + off);

    gate_gemm_kernel<<<NBLK * SPLITK, 256, 0, stream>>>(x, wg, part);
    softmax_kernel<<<NBLK, 256, 0, stream>>>(part, gate_s, expert, rank, hist, partial_g);
    scan_kernel<<<1, 64, 0, stream>>>(hist, partial_g, chunk_b, l_aux_ws);
    // 537 MB zero-fill on the rocclr fill path (measured ~6.3 TB/s)
    hipMemsetAsync(d_out, 0, (size_t)out_size * sizeof(float), stream);
    scatter_kernel<<<(S_TOK + 255) / 256, 256, 0, stream>>>(gate_s, expert, rank,
                                                            chunk_b, l_aux_ws, out);
}